// Round 3
// baseline (338.156 us; speedup 1.0000x reference)
//
#include <hip/hip_runtime.h>
#include <math.h>

#define H 4096
#define NB_GEMV 1024   // blocks covering the 4*H matrix rows (16 rows/block)

typedef float nfloat4 __attribute__((ext_vector_type(4)));   // native vec for nt-store

__device__ __forceinline__ float wave_reduce_sum(float v) {
    #pragma unroll
    for (int off = 32; off > 0; off >>= 1)
        v += __shfl_down(v, off, 64);
    return v;
}

__device__ __forceinline__ float sigmoidf_(float x) {
    return 1.0f / (1.0f + __expf(-x));
}

// Kernel 1: four GEMVs (16 rows/block, x staged in LDS, 16-deep load bursts)
// plus two special blocks for the wi/wf scalar-gate dots.
__global__ __launch_bounds__(256, 4) void gemv_all(
    const float* __restrict__ x,
    const float* __restrict__ Wq, const float* __restrict__ Wk,
    const float* __restrict__ Wv, const float* __restrict__ Wo,
    const float* __restrict__ bq, const float* __restrict__ bk,
    const float* __restrict__ bv, const float* __restrict__ bo,
    const float* __restrict__ wi, const float* __restrict__ wf,
    float* __restrict__ q, float* __restrict__ k,
    float* __restrict__ v, float* __restrict__ og,
    float* __restrict__ s2)
{
    __shared__ float4 xs[H / 4];      // 16 KB
    __shared__ float red[4];
    const int t = threadIdx.x;
    const float4* x4 = (const float4*)x;

    if (blockIdx.x >= NB_GEMV) {
        // scalar gate dot products: block NB_GEMV -> wi.x, NB_GEMV+1 -> wf.x
        const float4* w4 = (const float4*)((blockIdx.x == NB_GEMV) ? wi : wf);
        float s = 0.0f;
        #pragma unroll
        for (int i = 0; i < 4; ++i) {
            float4 a = w4[i * 256 + t];
            float4 b = x4[i * 256 + t];
            s += a.x * b.x + a.y * b.y + a.z * b.z + a.w * b.w;
        }
        s = wave_reduce_sum(s);
        const int wave = t >> 6, lane = t & 63;
        if (lane == 0) red[wave] = s;
        __syncthreads();
        if (t == 0) s2[blockIdx.x - NB_GEMV] = red[0] + red[1] + red[2] + red[3];
        return;
    }

    // stage x into LDS (removes x from the vmcnt queue in the hot loop)
    #pragma unroll
    for (int i = 0; i < 4; ++i) xs[i * 256 + t] = x4[i * 256 + t];
    __syncthreads();

    const int wave = t >> 6, lane = t & 63;
    const int rowBase = blockIdx.x * 16;        // 16 rows per block, same matrix
    const int m = rowBase >> 12;                // which of the 4 matrices
    const float* W = (m == 0) ? Wq : (m == 1) ? Wk : (m == 2) ? Wv : Wo;

    #pragma unroll 1
    for (int i = 0; i < 4; ++i) {
        const int r = (rowBase & (H - 1)) + i * 4 + wave;   // 4 waves on 4 adjacent rows
        const float4* row4 = (const float4*)(W + (size_t)r * H);

        // 16-deep global load burst into registers
        float4 a[16];
        #pragma unroll
        for (int it = 0; it < 16; ++it) a[it] = row4[it * 64 + lane];

        float acc = 0.0f;
        #pragma unroll
        for (int it = 0; it < 16; ++it) {
            float4 b = xs[it * 64 + lane];
            acc += a[it].x * b.x + a[it].y * b.y + a[it].z * b.z + a[it].w * b.w;
        }
        acc = wave_reduce_sum(acc);

        if (lane == 0) {
            if (m == 0)      q[r]  = acc + bq[r];
            else if (m == 1) k[r]  = (acc + bk[r]) * 0.015625f;   // 1/sqrt(4096)
            else if (m == 2) v[r]  = acc + bv[r];
            else             og[r] = sigmoidf_(acc + bo[r]);
        }
    }
}

// Kernel 2: C = f*C_prev + (i*v[r])*k (-> d_out), u[r] = C_prev[r,:].q fused.
// q,k staged in LDS; 16-deep C_prev load burst; nontemporal C stores.
__global__ __launch_bounds__(256, 2) void c_update(
    const float* __restrict__ C_prev,
    const float* __restrict__ q, const float* __restrict__ k,
    const float* __restrict__ v, const float* __restrict__ s2,
    const float* __restrict__ bi, const float* __restrict__ bf,
    float* __restrict__ C_out, float* __restrict__ u)
{
    __shared__ float4 qs[H / 4];      // 16 KB
    __shared__ float4 ks[H / 4];      // 16 KB
    const int t = threadIdx.x;
    const float4* q4 = (const float4*)q;
    const float4* k4 = (const float4*)k;
    #pragma unroll
    for (int i = 0; i < 4; ++i) {
        qs[i * 256 + t] = q4[i * 256 + t];
        ks[i * 256 + t] = k4[i * 256 + t];
    }
    __syncthreads();

    const int wave = t >> 6, lane = t & 63;
    const float ig = __expf(s2[0] + bi[0]);
    const float fg = sigmoidf_(s2[1] + bf[0]);

    #pragma unroll 1
    for (int i = 0; i < 2; ++i) {                 // 8 rows/block, 2 per wave
        const int r = blockIdx.x * 8 + i * 4 + wave;
        const float4* c4 = (const float4*)(C_prev + (size_t)r * H);
        nfloat4*      o4 = (nfloat4*)(C_out + (size_t)r * H);
        const float ivr = ig * v[r];

        float4 c[16];
        #pragma unroll
        for (int it = 0; it < 16; ++it) c[it] = c4[it * 64 + lane];

        float acc = 0.0f;
        #pragma unroll
        for (int it = 0; it < 16; ++it) {
            float4 qq = qs[it * 64 + lane];
            float4 kk = ks[it * 64 + lane];
            nfloat4 o;
            o.x = fg * c[it].x + ivr * kk.x;
            o.y = fg * c[it].y + ivr * kk.y;
            o.z = fg * c[it].z + ivr * kk.z;
            o.w = fg * c[it].w + ivr * kk.w;
            __builtin_nontemporal_store(o, &o4[it * 64 + lane]);
            acc += c[it].x * qq.x + c[it].y * qq.y + c[it].z * qq.z + c[it].w * qq.w;
        }
        acc = wave_reduce_sum(acc);
        if (lane == 0) u[r] = acc;
    }
}

// Kernel 3: n = f*n_prev + i*k (-> out); nq = n.q; kq = k.q;
// h = og * (f*u + i*v*kq) / max(|nq|,1). Single block, float4.
__global__ __launch_bounds__(1024) void finalize(
    const float* __restrict__ n_prev,
    const float* __restrict__ q, const float* __restrict__ k,
    const float* __restrict__ v, const float* __restrict__ og,
    const float* __restrict__ u, const float* __restrict__ s2,
    const float* __restrict__ bi, const float* __restrict__ bf,
    float* __restrict__ h, float* __restrict__ n_out)
{
    const int t = threadIdx.x;
    const int wave = t >> 6;
    const int lane = t & 63;

    const float ig = __expf(s2[0] + bi[0]);
    const float fg = sigmoidf_(s2[1] + bf[0]);

    const float4* q4  = (const float4*)q;
    const float4* k4  = (const float4*)k;
    const float4* np4 = (const float4*)n_prev;

    float4 qq = q4[t];
    float4 kk = k4[t];
    float4 nn = np4[t];
    float4 no;
    no.x = fg * nn.x + ig * kk.x;
    no.y = fg * nn.y + ig * kk.y;
    no.z = fg * nn.z + ig * kk.z;
    no.w = fg * nn.w + ig * kk.w;
    ((float4*)n_out)[t] = no;

    float nq = no.x * qq.x + no.y * qq.y + no.z * qq.z + no.w * qq.w;
    float kq = kk.x * qq.x + kk.y * qq.y + kk.z * qq.z + kk.w * qq.w;
    nq = wave_reduce_sum(nq);
    kq = wave_reduce_sum(kq);

    __shared__ float snq[16], skq[16];
    if (lane == 0) { snq[wave] = nq; skq[wave] = kq; }
    __syncthreads();
    if (t == 0) {
        float a = 0.0f, b = 0.0f;
        #pragma unroll
        for (int w = 0; w < 16; ++w) { a += snq[w]; b += skq[w]; }
        snq[0] = a; skq[0] = b;
    }
    __syncthreads();

    const float denom = fmaxf(fabsf(snq[0]), 1.0f);
    const float kqv = skq[0];
    const float inv_denom = 1.0f / denom;

    const float4* v4  = (const float4*)v;
    const float4* og4 = (const float4*)og;
    const float4* u4  = (const float4*)u;
    float4 vv = v4[t];
    float4 oo = og4[t];
    float4 uu = u4[t];
    float4 hh;
    hh.x = oo.x * (fg * uu.x + ig * vv.x * kqv) * inv_denom;
    hh.y = oo.y * (fg * uu.y + ig * vv.y * kqv) * inv_denom;
    hh.z = oo.z * (fg * uu.z + ig * vv.z * kqv) * inv_denom;
    hh.w = oo.w * (fg * uu.w + ig * vv.w * kqv) * inv_denom;
    ((float4*)h)[t] = hh;
}

extern "C" void kernel_launch(void* const* d_in, const int* in_sizes, int n_in,
                              void* d_out, int out_size, void* d_ws, size_t ws_size,
                              hipStream_t stream) {
    const float* x      = (const float*)d_in[0];
    // d_in[1] = h_prev (unused by mLSTM math)
    const float* C_prev = (const float*)d_in[2];
    const float* n_prev = (const float*)d_in[3];
    const float* Wq     = (const float*)d_in[4];
    const float* Wk     = (const float*)d_in[5];
    const float* Wv     = (const float*)d_in[6];
    const float* Wo     = (const float*)d_in[7];
    const float* bq     = (const float*)d_in[8];
    const float* bk     = (const float*)d_in[9];
    const float* bv     = (const float*)d_in[10];
    const float* bo     = (const float*)d_in[11];
    const float* wi     = (const float*)d_in[12];
    const float* bi     = (const float*)d_in[13];
    const float* wf     = (const float*)d_in[14];
    const float* bf     = (const float*)d_in[15];

    float* out   = (float*)d_out;
    float* h_out = out;                       // [H]
    float* C_out = out + H;                   // [H*H]
    float* n_out = out + H + (size_t)H * H;   // [H]

    float* ws = (float*)d_ws;
    float* q  = ws;
    float* k  = ws + H;
    float* v  = ws + 2 * H;
    float* og = ws + 3 * H;
    float* u  = ws + 4 * H;
    float* s2 = ws + 5 * H;                   // 2 floats

    // Kernel 1: 1024 matrix blocks + 2 dot blocks.
    gemv_all<<<NB_GEMV + 2, 256, 0, stream>>>(x, Wq, Wk, Wv, Wo, bq, bk, bv, bo,
                                              wi, wf, q, k, v, og, s2);

    // Kernel 2: 8 rows per block.
    c_update<<<H / 8, 256, 0, stream>>>(C_prev, q, k, v, s2, bi, bf, C_out, u);

    // Kernel 3: single block epilogue.
    finalize<<<1, 1024, 0, stream>>>(n_prev, q, k, v, og, u, s2, bi, bf,
                                     h_out, n_out);
}